// Round 10
// baseline (96.025 us; speedup 1.0000x reference)
//
#include <hip/hip_runtime.h>
#include <hip/hip_bf16.h>
#include <stdint.h>

typedef __hip_bfloat16 bf16;
typedef __attribute__((ext_vector_type(8))) short bf16x8;
typedef __attribute__((ext_vector_type(4))) float f32x4;
typedef __attribute__((ext_vector_type(16))) float f32x16;

#define MFMA16(a, b, c) __builtin_amdgcn_mfma_f32_16x16x32_bf16(a, b, c, 0, 0, 0)
#define MFMA32(a, b, c) __builtin_amdgcn_mfma_f32_32x32x16_bf16(a, b, c, 0, 0, 0)

__device__ __forceinline__ void gl_lds16(const void* g, void* l) {
  __builtin_amdgcn_global_load_lds(
      (const __attribute__((address_space(1))) uint32_t*)g,
      (__attribute__((address_space(3))) uint32_t*)l, 16, 0, 0);
}

// ---------------- fused prep: casts + RoPE table (one launch) ----------------
struct alignas(8) bf16x4s { bf16 a, b, c, d; };

__device__ __forceinline__ void cast4(const float* __restrict__ src,
                                      bf16* __restrict__ dst, int i) {
  float4 v = ((const float4*)src)[i];
  bf16x4s o{__float2bfloat16(v.x), __float2bfloat16(v.y),
            __float2bfloat16(v.z), __float2bfloat16(v.w)};
  ((bf16x4s*)dst)[i] = o;
}

__global__ void k_prep(const float* __restrict__ x, const float* __restrict__ qkvw,
                       const float* __restrict__ projw, bf16* __restrict__ xb,
                       bf16* __restrict__ wqkvb, bf16* __restrict__ wprojb,
                       float* __restrict__ cosT, float* __restrict__ sinT) {
  const int bid = blockIdx.x, tid = threadIdx.x;
  if (bid < 3072) {            // x: 786432 float4
    cast4(x, xb, bid * 256 + tid);
  } else if (bid < 4800) {     // qkv_w: 442368 float4
    cast4(qkvw, wqkvb, (bid - 3072) * 256 + tid);
  } else if (bid < 5376) {     // proj_w: 147456 float4
    cast4(projw, wprojb, (bid - 4800) * 256 + tid);
  } else {                     // cis table: 32768 entries
    const int i = (bid - 5376) * 256 + tid;
    const int pos = i >> 5, p = i & 31;
    const int j = p & 15;
    const float t = (p < 16) ? (float)(pos & 31) : (float)(pos >> 5);
    const float f = powf(10000.0f, -(float)j / 16.0f);
    float sv, cv;
    sincosf(t * f, &sv, &cv);
    cosT[i] = cv;
    sinT[i] = sv;
  }
}

// ------- BM x BN tile GEMM mainloop, BK=32, counted-vmcnt 2-barrier -------
// C^T via OPERAND-SWAPPED MFMA. acc[fm*FN+fn] reg r holds value at
// n = n0 + wn*(BN/2) + fn*16 + lg*4 + r, m = m0 + wm*(BM/2) + fm*16 + lr.
template <int BM, int BN>
__device__ __forceinline__ void gemm_loop(const bf16* __restrict__ A,
                                          const bf16* __restrict__ Bt,
                                          int m0, int n0, bf16* ldsA, bf16* ldsB,
                                          f32x4* acc) {
  constexpr int FM = BM / 32, FN = BN / 32;
  constexpr int AL = BM / 64, BL = BN / 64;   // gl_lds16 per thread per stage
  constexpr int ABYTES = BM * 64, BBYTES = BN * 64;
  const int tid = threadIdx.x;
  const int lane = tid & 63, w = tid >> 6;
  const int wm = w >> 1, wn = w & 1;
  const int lr = lane & 15, lg = lane >> 4;

  auto stage = [&](int kt, int buf) {
#pragma unroll
    for (int c = 0; c < AL; ++c) {
      const int o = c * 4096 + w * 1024 + lane * 16;  // byte in [BM][32]bf16 tile
      gl_lds16((const char*)A + ((size_t)(m0 + (o >> 6)) * 768 + kt) * 2 + (o & 63),
               (char*)ldsA + buf * ABYTES + c * 4096 + w * 1024);
    }
#pragma unroll
    for (int c = 0; c < BL; ++c) {
      const int o = c * 4096 + w * 1024 + lane * 16;
      gl_lds16((const char*)Bt + ((size_t)(n0 + (o >> 6)) * 768 + kt) * 2 + (o & 63),
               (char*)ldsB + buf * BBYTES + c * 4096 + w * 1024);
    }
  };

  stage(0, 0);
  int cur = 0;
  for (int ki = 0; ki < 24; ++ki) {
    if (ki + 1 < 24) {
      stage((ki + 1) * 32, cur ^ 1);  // next tile's loads stay in flight
      if constexpr (AL + BL == 2) asm volatile("s_waitcnt vmcnt(2)" ::: "memory");
      else if constexpr (AL + BL == 3) asm volatile("s_waitcnt vmcnt(3)" ::: "memory");
      else asm volatile("s_waitcnt vmcnt(4)" ::: "memory");
    } else {
      asm volatile("s_waitcnt vmcnt(0)" ::: "memory");
    }
    __builtin_amdgcn_s_barrier();     // all waves: buf[cur] staged
    const char* baseA = (const char*)ldsA + cur * ABYTES;
    const char* baseB = (const char*)ldsB + cur * BBYTES;
    bf16x8 af[FM], bf_[FN];
#pragma unroll
    for (int f = 0; f < FM; ++f)
      af[f] = *(const bf16x8*)(baseA + (wm * (BM / 2) + f * 16 + lr) * 64 + lg * 16);
#pragma unroll
    for (int f = 0; f < FN; ++f)
      bf_[f] = *(const bf16x8*)(baseB + (wn * (BN / 2) + f * 16 + lr) * 64 + lg * 16);
    __builtin_amdgcn_s_setprio(1);
#pragma unroll
    for (int fm = 0; fm < FM; ++fm)
#pragma unroll
      for (int fn = 0; fn < FN; ++fn)
        acc[fm * FN + fn] = MFMA16(bf_[fn], af[fm], acc[fm * FN + fn]);  // D^T
    __builtin_amdgcn_s_setprio(0);
    asm volatile("s_waitcnt lgkmcnt(0)" ::: "memory");  // my ds_reads done
    __builtin_amdgcn_s_barrier();                       // safe to overwrite buf[cur]
    cur ^= 1;
  }
}

// ---------------- QKV GEMM + bias + RoPE epilogue (64x128 tiles, D^T) ----------------
__global__ __launch_bounds__(256, 6) void k_qkv(
    const bf16* __restrict__ xb, const bf16* __restrict__ wb, const float* __restrict__ qkvb,
    const float* __restrict__ cosT, const float* __restrict__ sinT,
    bf16* __restrict__ Qb, bf16* __restrict__ Kb, bf16* __restrict__ VbT) {
  __shared__ __align__(16) bf16 ldsA[2][64 * 32];
  __shared__ __align__(16) bf16 ldsB[2][128 * 32];
  const int m0 = (blockIdx.x & 63) * 64, n0 = (blockIdx.x >> 6) * 128;  // 64 x 18 tiles
  f32x4 acc[2 * 4] = {};
  gemm_loop<64, 128>(xb, wb, m0, n0, &ldsA[0][0], &ldsB[0][0], acc);
  const int lane = threadIdx.x & 63, w = threadIdx.x >> 6;
  const int wm = w >> 1, wn = w & 1, lr = lane & 15, lg = lane >> 4;
#pragma unroll
  for (int fm = 0; fm < 2; ++fm) {
    const int m = m0 + wm * 32 + fm * 16 + lr;
    const int bb = m >> 10, pos = m & 1023;
#pragma unroll
    for (int fn = 0; fn < 4; ++fn) {
      const int nb = n0 + wn * 64 + fn * 16 + lg * 4;  // base n for r=0..3 (mult of 4)
      const int sect = nb / 768;                       // 0=q 1=k 2=v (uniform per 4-block)
      const int cnb = nb - sect * 768;
      const int head = cnb >> 6, db = cnb & 63;        // db mult of 4
      const float4 b4 = *(const float4*)(qkvb + nb);
      const f32x4 a = acc[fm * 4 + fn];
      const float v0 = a[0] + b4.x, v1 = a[1] + b4.y;
      const float v2 = a[2] + b4.z, v3 = a[3] + b4.w;
      const size_t base = (size_t)(bb * 12 + head) * 65536;
      if (sect < 2) {
        const int p0 = db >> 1;                        // pairs (r0,r1)->p0, (r2,r3)->p0+1
        const float c0 = cosT[pos * 32 + p0], s0 = sinT[pos * 32 + p0];
        const float c1 = cosT[pos * 32 + p0 + 1], s1 = sinT[pos * 32 + p0 + 1];
        short4 st;
        ((bf16*)&st)[0] = __float2bfloat16(v0 * c0 - v1 * s0);
        ((bf16*)&st)[1] = __float2bfloat16(v1 * c0 + v0 * s0);
        ((bf16*)&st)[2] = __float2bfloat16(v2 * c1 - v3 * s1);
        ((bf16*)&st)[3] = __float2bfloat16(v3 * c1 + v2 * s1);
        bf16* dst = (sect == 0 ? Qb : Kb) + base + (size_t)pos * 64 + db;
        *(short4*)dst = st;
      } else {
        VbT[base + (size_t)(db + 0) * 1024 + pos] = __float2bfloat16(v0);
        VbT[base + (size_t)(db + 1) * 1024 + pos] = __float2bfloat16(v1);
        VbT[base + (size_t)(db + 2) * 1024 + pos] = __float2bfloat16(v2);
        VbT[base + (size_t)(db + 3) * 1024 + pos] = __float2bfloat16(v3);
      }
    }
  }
}

// ---------------- decomposed rel-pos bias tables via MFMA (no LDS) ----------------
__global__ __launch_bounds__(256) void k_relbias(
    const bf16* __restrict__ Qb, const float* __restrict__ relph,
    const float* __restrict__ relpw, float* __restrict__ relh,
    float* __restrict__ relw) {
  const int bid = blockIdx.x;          // 768 = 48 bn * 2 part * 8 rc-groups
  const int bn = bid >> 4;
  const int rem = bid & 15;
  const bool isW = (rem >> 3) != 0;
  const int w = threadIdx.x >> 6;
  const int rc = (rem & 7) * 4 + w;    // 0..31
  const int lane = threadIdx.x & 63;
  const int lr = lane & 15, lg = lane >> 4;
  const float* __restrict__ relp = isW ? relpw : relph;

  bf16x8 af[2][2];   // A = Q rows; [m-block][k-step]
#pragma unroll
  for (int mb = 0; mb < 2; ++mb) {
    const int m = mb * 16 + lr;
    const int l = isW ? (m * 32 + rc) : (rc * 32 + m);
    const bf16* ap = Qb + (size_t)bn * 65536 + (size_t)l * 64 + lg * 8;
#pragma unroll
    for (int ks = 0; ks < 2; ++ks) af[mb][ks] = *(const bf16x8*)(ap + ks * 32);
  }
  bf16x8 bfr[2][2];  // B = rel_pos rows (fp32 -> bf16); [n-block][k-step]
#pragma unroll
  for (int nb = 0; nb < 2; ++nb) {
    const int n = nb * 16 + lr;
    const float* bp = relp + (size_t)(31 + rc - n) * 64 + lg * 8;
#pragma unroll
    for (int ks = 0; ks < 2; ++ks) {
      const float4 f0 = *(const float4*)(bp + ks * 32);
      const float4 f1 = *(const float4*)(bp + ks * 32 + 4);
      bf16x8 t;
      ((bf16*)&t)[0] = __float2bfloat16(f0.x);
      ((bf16*)&t)[1] = __float2bfloat16(f0.y);
      ((bf16*)&t)[2] = __float2bfloat16(f0.z);
      ((bf16*)&t)[3] = __float2bfloat16(f0.w);
      ((bf16*)&t)[4] = __float2bfloat16(f1.x);
      ((bf16*)&t)[5] = __float2bfloat16(f1.y);
      ((bf16*)&t)[6] = __float2bfloat16(f1.z);
      ((bf16*)&t)[7] = __float2bfloat16(f1.w);
      bfr[nb][ks] = t;
    }
  }
  f32x4 acc[2][2] = {};
#pragma unroll
  for (int ks = 0; ks < 2; ++ks)
#pragma unroll
    for (int mb = 0; mb < 2; ++mb)
#pragma unroll
      for (int nb = 0; nb < 2; ++nb)
        acc[mb][nb] = MFMA16(af[mb][ks], bfr[nb][ks], acc[mb][nb]);
  float* __restrict__ dst = isW ? relw : relh;
#pragma unroll
  for (int mb = 0; mb < 2; ++mb)
#pragma unroll
    for (int nb = 0; nb < 2; ++nb)
#pragma unroll
      for (int r = 0; r < 4; ++r) {
        const int mo = mb * 16 + lg * 4 + r;
        const int n = nb * 16 + lr;
        const int l = isW ? (mo * 32 + rc) : (rc * 32 + mo);
        dst[(size_t)bn * 32768 + (size_t)l * 32 + n] = acc[mb][nb][r];
      }
}

// ---------------- flash attention: 128-thread block = (bn, 64-row q-tile) ----------------
// 2 waves x 32 q-rows via 32x32x16 MFMA; P stays IN REGISTERS (cvt_pk +
// permlane32_swap: vdst hi-lanes <-> vsrc lo-lanes, so A-pack is vdst).
// No-max softmax (scores bounded); counted-vmcnt 2-barrier K/V pipeline;
// XCD-chunked swizzle (768 = 8*96, bijective).
__global__ __launch_bounds__(128, 2) void k_attn(
    const bf16* __restrict__ Qb, const bf16* __restrict__ Kb, const bf16* __restrict__ VbT,
    const float* __restrict__ relh, const float* __restrict__ relw, bf16* __restrict__ attno) {
  __shared__ __align__(16) bf16 Kt[2][64 * 64];   // [key][ch], XOR-swizzled rows
  __shared__ __align__(16) bf16 Vt[2][64 * 64];   // [d][key] (V^T), XOR-swizzled rows
  __shared__ __align__(16) float bH[64 * 34];     // rel_h slice, stride 34 (8B rows)
  const int blk0 = blockIdx.x;                    // 768 = 48 bn * 16 qtiles
  const int blk = (blk0 & 7) * 96 + (blk0 >> 3);  // XCD-chunked swizzle
  const int bn = blk >> 4, qt = blk & 15;
  const int b = bn / 12, head = bn - b * 12;
  const int tid = threadIdx.x;                    // 0..127
  const int w = tid >> 6, lane = tid & 63;
  const int qc = lane & 31, hi = lane >> 5;
  const size_t qkvbase = (size_t)bn * 65536;

  auto stageKV = [&](int kt, int buf) {
#pragma unroll
    for (int c = 0; c < 4; ++c) {
      const int o = c * 2048 + w * 1024 + lane * 16;  // byte in 8KB tile
      const int row = o >> 7;
      const int loff = o ^ ((row & 7) << 4);          // pre-swizzled source (rule #21)
      gl_lds16((const char*)Kb + (qkvbase + (size_t)kt * 4096) * 2 + loff,
               (char*)Kt + buf * 8192 + c * 2048 + w * 1024);
      gl_lds16((const char*)VbT + (qkvbase + (size_t)row * 1024 + (size_t)kt * 64) * 2 + (loff & 127),
               (char*)Vt + buf * 8192 + c * 2048 + w * 1024);
    }
  };

  stageKV(0, 0);
  {  // stage bH: 64 rows x 32 floats; float2 (8B) stores -- stride-34 rows are only
     // 8B-aligned for odd rows, so b128 stores would be misaligned (round-9 bug #2)
    const int r = tid >> 1, h16 = (tid & 1) * 16;
    const float* src = relh + (size_t)bn * 32768 + (size_t)(qt * 64 + r) * 32 + h16;
    float* dst = &bH[r * 34 + h16];
#pragma unroll
    for (int j = 0; j < 8; ++j) *(float2*)(dst + j * 2) = *(const float2*)(src + j * 2);
  }
  const int q_g = qt * 64 + w * 32 + qc;
  bf16x8 qf[4];  // Q B-frags: Q[q_g][s*16 + hi*8 + j]
  {
    const char* qp = (const char*)Qb + (qkvbase + (size_t)q_g * 64) * 2;
#pragma unroll
    for (int s = 0; s < 4; ++s) qf[s] = *(const bf16x8*)(qp + s * 32 + hi * 16);
  }
  float bwv[16];  // rel_w[q_g][lk(reg,hi)]; lk = (reg&3) + 8*(reg>>2) + 4*hi (static idx)
  {
    const float* rw = relw + (size_t)bn * 32768 + (size_t)q_g * 32 + hi * 4;
#pragma unroll
    for (int rg = 0; rg < 4; ++rg) {
      const float4 v = *(const float4*)(rw + rg * 8);
      bwv[rg * 4 + 0] = v.x; bwv[rg * 4 + 1] = v.y;
      bwv[rg * 4 + 2] = v.z; bwv[rg * 4 + 3] = v.w;
    }
  }
  f32x16 oacc[2] = {};  // O^T: col q = qc; row d = dblk*32 + (reg&3)+8*(reg>>2)+4*hi
  float psum = 0.0f;    // this lane's 32-of-64 keys per iter; partner (lane^32) has rest
  asm volatile("s_waitcnt lgkmcnt(0)" ::: "memory");  // bH wave-local writes visible
  int cur = 0;

  for (int kt = 0; kt < 16; ++kt) {
    if (kt + 1 < 16) {
      stageKV(kt + 1, cur ^ 1);                         // 8 more loads in flight
      asm volatile("s_waitcnt vmcnt(8)" ::: "memory");  // stage(kt) landed (this wave)
    } else {
      asm volatile("s_waitcnt vmcnt(0)" ::: "memory");
    }
    __builtin_amdgcn_s_barrier();                       // both waves: Kt/Vt[cur] staged
    const char* Ktc = (const char*)Kt + cur * 8192;
    const char* Vtc = (const char*)Vt + cur * 8192;
    // QK^T: S^T[key][q] 32x32 per key-block; A = K-frag, B = Q-frag
    f32x16 sacc[2] = {};
    __builtin_amdgcn_s_setprio(1);
#pragma unroll
    for (int kb = 0; kb < 2; ++kb) {
      const int row = kb * 32 + qc;
      const int rb = row * 128, sw = (row & 7) << 4;
#pragma unroll
      for (int s = 0; s < 4; ++s) {
        const bf16x8 kf = *(const bf16x8*)(Ktc + ((rb + s * 32 + hi * 16) ^ sw));
        sacc[kb] = MFMA32(kf, qf[s], sacc[kb]);
      }
    }
    __builtin_amdgcn_s_setprio(0);
    // softmax (no-max) + in-register P^T frag build (T12)
    const float2 bh2 = *(const float2*)&bH[(w * 32 + qc) * 34 + 2 * kt];
    bf16x8 pb[4];
#pragma unroll
    for (int kb = 0; kb < 2; ++kb) {
      const float bh = (kb == 0) ? bh2.x : bh2.y;
      float pe[16];
#pragma unroll
      for (int reg = 0; reg < 16; ++reg) {
        const float p = __expf(sacc[kb][reg] * 0.125f + bh + bwv[reg]);
        psum += p;
        pe[reg] = p;
      }
      uint32_t A0, A1, B0, B1, C0, C1, D0, D1;
      asm("v_cvt_pk_bf16_f32 %0, %1, %2" : "=v"(A0) : "v"(pe[0]), "v"(pe[1]));
      asm("v_cvt_pk_bf16_f32 %0, %1, %2" : "=v"(A1) : "v"(pe[2]), "v"(pe[3]));
      asm("v_cvt_pk_bf16_f32 %0, %1, %2" : "=v"(B0) : "v"(pe[4]), "v"(pe[5]));
      asm("v_cvt_pk_bf16_f32 %0, %1, %2" : "=v"(B1) : "v"(pe[6]), "v"(pe[7]));
      asm("v_cvt_pk_bf16_f32 %0, %1, %2" : "=v"(C0) : "v"(pe[8]), "v"(pe[9]));
      asm("v_cvt_pk_bf16_f32 %0, %1, %2" : "=v"(C1) : "v"(pe[10]), "v"(pe[11]));
      asm("v_cvt_pk_bf16_f32 %0, %1, %2" : "=v"(D0) : "v"(pe[12]), "v"(pe[13]));
      asm("v_cvt_pk_bf16_f32 %0, %1, %2" : "=v"(D1) : "v"(pe[14]), "v"(pe[15]));
      // permlane32_swap: vdst[32:63] <-> vsrc[0:31]. A-pack MUST be vdst (round-9
      // bug #1 had it reversed): after swap, for hi=0: A=own lk{0..3}, B=partner
      // lk{4..7}; for hi=1: A=partner lk{8..11}, B=own lk{12..15}.
      asm volatile("v_permlane32_swap_b32 %0, %1" : "+v"(A0), "+v"(B0));
      asm volatile("v_permlane32_swap_b32 %0, %1" : "+v"(A1), "+v"(B1));
      asm volatile("v_permlane32_swap_b32 %0, %1" : "+v"(C0), "+v"(D0));
      asm volatile("v_permlane32_swap_b32 %0, %1" : "+v"(C1), "+v"(D1));
      union { uint32_t u[4]; bf16x8 v8; } u0, u1;
      u0.u[0] = A0; u0.u[1] = A1; u0.u[2] = B0; u0.u[3] = B1;
      u1.u[0] = C0; u1.u[1] = C1; u1.u[2] = D0; u1.u[3] = D1;
      pb[2 * kb] = u0.v8;
      pb[2 * kb + 1] = u1.v8;
    }
    // PV: O^T[d][q] += V^T-frag (A) x P^T-frag (B)
    __builtin_amdgcn_s_setprio(1);
#pragma unroll
    for (int dblk = 0; dblk < 2; ++dblk) {
      const int row = dblk * 32 + qc;
      const int rb = row * 128, sw = (row & 7) << 4;
#pragma unroll
      for (int s = 0; s < 4; ++s) {
        const bf16x8 vf = *(const bf16x8*)(Vtc + ((rb + s * 32 + hi * 16) ^ sw));
        oacc[dblk] = MFMA32(vf, pb[s], oacc[dblk]);
      }
    }
    __builtin_amdgcn_s_setprio(0);
    asm volatile("s_waitcnt lgkmcnt(0)" ::: "memory");  // my Kt/Vt ds_reads done
    __builtin_amdgcn_s_barrier();                       // safe to overwrite Kt/Vt[cur]
    cur ^= 1;
  }
  // combine the two key-halves (lane <-> lane^32 share q), normalize, store
  psum += __shfl_xor(psum, 32);
  const float inv = 1.0f / psum;
  bf16* obase = attno + ((size_t)b * 1024 + q_g) * 768 + head * 64;
#pragma unroll
  for (int dblk = 0; dblk < 2; ++dblk) {
#pragma unroll
    for (int rg = 0; rg < 4; ++rg) {
      short4 st;
#pragma unroll
      for (int j = 0; j < 4; ++j)
        ((bf16*)&st)[j] = __float2bfloat16(oacc[dblk][rg * 4 + j] * inv);
      *(short4*)(obase + dblk * 32 + rg * 8 + hi * 4) = st;
    }
  }
}

// ---------------- output projection GEMM + bias (64x64 tiles, D^T, fp32 out) ----------------
__global__ __launch_bounds__(256, 4) void k_proj(
    const bf16* __restrict__ attno, const bf16* __restrict__ pwb,
    const float* __restrict__ projb, float* __restrict__ out) {
  __shared__ __align__(16) bf16 ldsA[2][64 * 32];
  __shared__ __align__(16) bf16 ldsB[2][64 * 32];
  const int m0 = (blockIdx.x & 63) * 64, n0 = (blockIdx.x >> 6) * 64;  // 64 x 12 tiles
  f32x4 acc[2 * 2] = {};
  gemm_loop<64, 64>(attno, pwb, m0, n0, &ldsA[0][0], &ldsB[0][0], acc);
  const int lane = threadIdx.x & 63, w = threadIdx.x >> 6;
  const int wm = w >> 1, wn = w & 1, lr = lane & 15, lg = lane >> 4;
#pragma unroll
  for (int fm = 0; fm < 2; ++fm) {
    const int m = m0 + wm * 32 + fm * 16 + lr;
#pragma unroll
    for (int fn = 0; fn < 2; ++fn) {
      const int nb = n0 + wn * 32 + fn * 16 + lg * 4;
      const float4 b4 = *(const float4*)(projb + nb);
      const f32x4 a = acc[fm * 2 + fn];
      float4 o{a[0] + b4.x, a[1] + b4.y, a[2] + b4.z, a[3] + b4.w};
      *(float4*)(out + (size_t)m * 768 + nb) = o;
    }
  }
}

// ---------------- launch ----------------
extern "C" void kernel_launch(void* const* d_in, const int* in_sizes, int n_in,
                              void* d_out, int out_size, void* d_ws, size_t ws_size,
                              hipStream_t stream) {
  const float* x     = (const float*)d_in[0];
  const float* qkvw  = (const float*)d_in[1];
  const float* qkvb  = (const float*)d_in[2];
  const float* projw = (const float*)d_in[3];
  const float* projb = (const float*)d_in[4];
  const float* relph = (const float*)d_in[5];
  const float* relpw = (const float*)d_in[6];
  float* out = (float*)d_out;
  char* ws = (char*)d_ws;

  bf16*  xb     = (bf16*)(ws);              // 6,291,456 B
  bf16*  wqkvb  = (bf16*)(ws + 6291456);    // 3,538,944
  bf16*  wprojb = (bf16*)(ws + 9830400);    // 1,179,648
  float* cosT   = (float*)(ws + 11010048);  // 131,072
  float* sinT   = (float*)(ws + 11141120);  // 131,072
  bf16*  Qb     = (bf16*)(ws + 11272192);   // 6,291,456
  bf16*  Kb     = (bf16*)(ws + 17563648);   // 6,291,456
  bf16*  VbT    = (bf16*)(ws + 23855104);   // 6,291,456
  float* relh   = (float*)(ws + 30146560);  // 6,291,456
  float* relw   = (float*)(ws + 36438016);  // 6,291,456
  bf16*  attno  = (bf16*)(ws + 42729472);   // 6,291,456 -> ends 49,020,928

  k_prep<<<5504, 256, 0, stream>>>(x, qkvw, projw, xb, wqkvb, wprojb, cosT, sinT);
  k_qkv<<<1152, 256, 0, stream>>>(xb, wqkvb, qkvb, cosT, sinT, Qb, Kb, VbT);
  k_relbias<<<768, 256, 0, stream>>>(Qb, relph, relpw, relh, relw);
  k_attn<<<768, 128, 0, stream>>>(Qb, Kb, VbT, relh, relw, attno);
  k_proj<<<768, 256, 0, stream>>>(attno, wprojb, projb, out);
}

// Round 11
// 91.452 us; speedup vs baseline: 1.0500x; 1.0500x over previous
//
#include <hip/hip_runtime.h>
#include <hip/hip_bf16.h>
#include <stdint.h>

typedef __hip_bfloat16 bf16;
typedef __attribute__((ext_vector_type(8))) short bf16x8;
typedef __attribute__((ext_vector_type(4))) float f32x4;

#define MFMA16(a, b, c) __builtin_amdgcn_mfma_f32_16x16x32_bf16(a, b, c, 0, 0, 0)

__device__ __forceinline__ void gl_lds16(const void* g, void* l) {
  __builtin_amdgcn_global_load_lds(
      (const __attribute__((address_space(1))) uint32_t*)g,
      (__attribute__((address_space(3))) uint32_t*)l, 16, 0, 0);
}

// ---------------- fused prep: casts + RoPE table (one launch) ----------------
struct alignas(8) bf16x4s { bf16 a, b, c, d; };

__device__ __forceinline__ void cast4(const float* __restrict__ src,
                                      bf16* __restrict__ dst, int i) {
  float4 v = ((const float4*)src)[i];
  bf16x4s o{__float2bfloat16(v.x), __float2bfloat16(v.y),
            __float2bfloat16(v.z), __float2bfloat16(v.w)};
  ((bf16x4s*)dst)[i] = o;
}

__global__ void k_prep(const float* __restrict__ x, const float* __restrict__ qkvw,
                       const float* __restrict__ projw, bf16* __restrict__ xb,
                       bf16* __restrict__ wqkvb, bf16* __restrict__ wprojb,
                       float* __restrict__ cosT, float* __restrict__ sinT) {
  const int bid = blockIdx.x, tid = threadIdx.x;
  if (bid < 3072) {            // x: 786432 float4
    cast4(x, xb, bid * 256 + tid);
  } else if (bid < 4800) {     // qkv_w: 442368 float4
    cast4(qkvw, wqkvb, (bid - 3072) * 256 + tid);
  } else if (bid < 5376) {     // proj_w: 147456 float4
    cast4(projw, wprojb, (bid - 4800) * 256 + tid);
  } else {                     // cis table: 32768 entries
    const int i = (bid - 5376) * 256 + tid;
    const int pos = i >> 5, p = i & 31;
    const int j = p & 15;
    const float t = (p < 16) ? (float)(pos & 31) : (float)(pos >> 5);
    const float f = powf(10000.0f, -(float)j / 16.0f);
    float sv, cv;
    sincosf(t * f, &sv, &cv);
    cosT[i] = cv;
    sinT[i] = sv;
  }
}

// ------- BM x BN tile GEMM mainloop, BK=32, counted-vmcnt 2-barrier -------
// C^T via OPERAND-SWAPPED MFMA. acc[fm*FN+fn] reg r holds value at
// n = n0 + wn*(BN/2) + fn*16 + lg*4 + r, m = m0 + wm*(BM/2) + fm*16 + lr.
template <int BM, int BN>
__device__ __forceinline__ void gemm_loop(const bf16* __restrict__ A,
                                          const bf16* __restrict__ Bt,
                                          int m0, int n0, bf16* ldsA, bf16* ldsB,
                                          f32x4* acc) {
  constexpr int FM = BM / 32, FN = BN / 32;
  constexpr int AL = BM / 64, BL = BN / 64;   // gl_lds16 per thread per stage
  constexpr int ABYTES = BM * 64, BBYTES = BN * 64;
  const int tid = threadIdx.x;
  const int lane = tid & 63, w = tid >> 6;
  const int wm = w >> 1, wn = w & 1;
  const int lr = lane & 15, lg = lane >> 4;

  auto stage = [&](int kt, int buf) {
#pragma unroll
    for (int c = 0; c < AL; ++c) {
      const int o = c * 4096 + w * 1024 + lane * 16;  // byte in [BM][32]bf16 tile
      gl_lds16((const char*)A + ((size_t)(m0 + (o >> 6)) * 768 + kt) * 2 + (o & 63),
               (char*)ldsA + buf * ABYTES + c * 4096 + w * 1024);
    }
#pragma unroll
    for (int c = 0; c < BL; ++c) {
      const int o = c * 4096 + w * 1024 + lane * 16;
      gl_lds16((const char*)Bt + ((size_t)(n0 + (o >> 6)) * 768 + kt) * 2 + (o & 63),
               (char*)ldsB + buf * BBYTES + c * 4096 + w * 1024);
    }
  };

  stage(0, 0);
  int cur = 0;
  for (int ki = 0; ki < 24; ++ki) {
    if (ki + 1 < 24) {
      stage((ki + 1) * 32, cur ^ 1);  // next tile's loads stay in flight
      if constexpr (AL + BL == 2) asm volatile("s_waitcnt vmcnt(2)" ::: "memory");
      else if constexpr (AL + BL == 3) asm volatile("s_waitcnt vmcnt(3)" ::: "memory");
      else asm volatile("s_waitcnt vmcnt(4)" ::: "memory");
    } else {
      asm volatile("s_waitcnt vmcnt(0)" ::: "memory");
    }
    __builtin_amdgcn_s_barrier();     // all waves: buf[cur] staged
    const char* baseA = (const char*)ldsA + cur * ABYTES;
    const char* baseB = (const char*)ldsB + cur * BBYTES;
    bf16x8 af[FM], bf_[FN];
#pragma unroll
    for (int f = 0; f < FM; ++f)
      af[f] = *(const bf16x8*)(baseA + (wm * (BM / 2) + f * 16 + lr) * 64 + lg * 16);
#pragma unroll
    for (int f = 0; f < FN; ++f)
      bf_[f] = *(const bf16x8*)(baseB + (wn * (BN / 2) + f * 16 + lr) * 64 + lg * 16);
    __builtin_amdgcn_s_setprio(1);
#pragma unroll
    for (int fm = 0; fm < FM; ++fm)
#pragma unroll
      for (int fn = 0; fn < FN; ++fn)
        acc[fm * FN + fn] = MFMA16(bf_[fn], af[fm], acc[fm * FN + fn]);  // D^T
    __builtin_amdgcn_s_setprio(0);
    asm volatile("s_waitcnt lgkmcnt(0)" ::: "memory");  // my ds_reads done
    __builtin_amdgcn_s_barrier();                       // safe to overwrite buf[cur]
    cur ^= 1;
  }
}

// ---------------- QKV GEMM + bias + RoPE epilogue (64x128 tiles, D^T) ----------------
__global__ __launch_bounds__(256, 6) void k_qkv(
    const bf16* __restrict__ xb, const bf16* __restrict__ wb, const float* __restrict__ qkvb,
    const float* __restrict__ cosT, const float* __restrict__ sinT,
    bf16* __restrict__ Qb, bf16* __restrict__ Kb, bf16* __restrict__ VbT) {
  __shared__ __align__(16) bf16 ldsA[2][64 * 32];
  __shared__ __align__(16) bf16 ldsB[2][128 * 32];
  const int m0 = (blockIdx.x & 63) * 64, n0 = (blockIdx.x >> 6) * 128;  // 64 x 18 tiles
  f32x4 acc[2 * 4] = {};
  gemm_loop<64, 128>(xb, wb, m0, n0, &ldsA[0][0], &ldsB[0][0], acc);
  const int lane = threadIdx.x & 63, w = threadIdx.x >> 6;
  const int wm = w >> 1, wn = w & 1, lr = lane & 15, lg = lane >> 4;
#pragma unroll
  for (int fm = 0; fm < 2; ++fm) {
    const int m = m0 + wm * 32 + fm * 16 + lr;
    const int bb = m >> 10, pos = m & 1023;
#pragma unroll
    for (int fn = 0; fn < 4; ++fn) {
      const int nb = n0 + wn * 64 + fn * 16 + lg * 4;  // base n for r=0..3 (mult of 4)
      const int sect = nb / 768;                       // 0=q 1=k 2=v (uniform per 4-block)
      const int cnb = nb - sect * 768;
      const int head = cnb >> 6, db = cnb & 63;        // db mult of 4
      const float4 b4 = *(const float4*)(qkvb + nb);
      const f32x4 a = acc[fm * 4 + fn];
      const float v0 = a[0] + b4.x, v1 = a[1] + b4.y;
      const float v2 = a[2] + b4.z, v3 = a[3] + b4.w;
      const size_t base = (size_t)(bb * 12 + head) * 65536;
      if (sect < 2) {
        const int p0 = db >> 1;                        // pairs (r0,r1)->p0, (r2,r3)->p0+1
        const float c0 = cosT[pos * 32 + p0], s0 = sinT[pos * 32 + p0];
        const float c1 = cosT[pos * 32 + p0 + 1], s1 = sinT[pos * 32 + p0 + 1];
        short4 st;
        ((bf16*)&st)[0] = __float2bfloat16(v0 * c0 - v1 * s0);
        ((bf16*)&st)[1] = __float2bfloat16(v1 * c0 + v0 * s0);
        ((bf16*)&st)[2] = __float2bfloat16(v2 * c1 - v3 * s1);
        ((bf16*)&st)[3] = __float2bfloat16(v3 * c1 + v2 * s1);
        bf16* dst = (sect == 0 ? Qb : Kb) + base + (size_t)pos * 64 + db;
        *(short4*)dst = st;
      } else {
        VbT[base + (size_t)(db + 0) * 1024 + pos] = __float2bfloat16(v0);
        VbT[base + (size_t)(db + 1) * 1024 + pos] = __float2bfloat16(v1);
        VbT[base + (size_t)(db + 2) * 1024 + pos] = __float2bfloat16(v2);
        VbT[base + (size_t)(db + 3) * 1024 + pos] = __float2bfloat16(v3);
      }
    }
  }
}

// ---------------- decomposed rel-pos bias tables via MFMA (no LDS) ----------------
__global__ __launch_bounds__(256) void k_relbias(
    const bf16* __restrict__ Qb, const float* __restrict__ relph,
    const float* __restrict__ relpw, float* __restrict__ relh,
    float* __restrict__ relw) {
  const int bid = blockIdx.x;          // 768 = 48 bn * 2 part * 8 rc-groups
  const int bn = bid >> 4;
  const int rem = bid & 15;
  const bool isW = (rem >> 3) != 0;
  const int w = threadIdx.x >> 6;
  const int rc = (rem & 7) * 4 + w;    // 0..31
  const int lane = threadIdx.x & 63;
  const int lr = lane & 15, lg = lane >> 4;
  const float* __restrict__ relp = isW ? relpw : relph;

  bf16x8 af[2][2];   // A = Q rows; [m-block][k-step]
#pragma unroll
  for (int mb = 0; mb < 2; ++mb) {
    const int m = mb * 16 + lr;
    const int l = isW ? (m * 32 + rc) : (rc * 32 + m);
    const bf16* ap = Qb + (size_t)bn * 65536 + (size_t)l * 64 + lg * 8;
#pragma unroll
    for (int ks = 0; ks < 2; ++ks) af[mb][ks] = *(const bf16x8*)(ap + ks * 32);
  }
  bf16x8 bfr[2][2];  // B = rel_pos rows (fp32 -> bf16); [n-block][k-step]
#pragma unroll
  for (int nb = 0; nb < 2; ++nb) {
    const int n = nb * 16 + lr;
    const float* bp = relp + (size_t)(31 + rc - n) * 64 + lg * 8;
#pragma unroll
    for (int ks = 0; ks < 2; ++ks) {
      const float4 f0 = *(const float4*)(bp + ks * 32);
      const float4 f1 = *(const float4*)(bp + ks * 32 + 4);
      bf16x8 t;
      ((bf16*)&t)[0] = __float2bfloat16(f0.x);
      ((bf16*)&t)[1] = __float2bfloat16(f0.y);
      ((bf16*)&t)[2] = __float2bfloat16(f0.z);
      ((bf16*)&t)[3] = __float2bfloat16(f0.w);
      ((bf16*)&t)[4] = __float2bfloat16(f1.x);
      ((bf16*)&t)[5] = __float2bfloat16(f1.y);
      ((bf16*)&t)[6] = __float2bfloat16(f1.z);
      ((bf16*)&t)[7] = __float2bfloat16(f1.w);
      bfr[nb][ks] = t;
    }
  }
  f32x4 acc[2][2] = {};
#pragma unroll
  for (int ks = 0; ks < 2; ++ks)
#pragma unroll
    for (int mb = 0; mb < 2; ++mb)
#pragma unroll
      for (int nb = 0; nb < 2; ++nb)
        acc[mb][nb] = MFMA16(af[mb][ks], bfr[nb][ks], acc[mb][nb]);
  float* __restrict__ dst = isW ? relw : relh;
#pragma unroll
  for (int mb = 0; mb < 2; ++mb)
#pragma unroll
    for (int nb = 0; nb < 2; ++nb)
#pragma unroll
      for (int r = 0; r < 4; ++r) {
        const int mo = mb * 16 + lg * 4 + r;
        const int n = nb * 16 + lr;
        const int l = isW ? (mo * 32 + rc) : (rc * 32 + mo);
        dst[(size_t)bn * 32768 + (size_t)l * 32 + n] = acc[mb][nb][r];
      }
}

// ---------------- flash attention: one block = (bn, 64-row q-tile) ----------------
// Round-8 proven structure: 256 threads / 4 waves x 16 q-rows (12 waves/CU --
// the 32x32 2-wave variant was grid-capped at 6 waves/CU and slower).
// No-max softmax; PV operand-swapped -> O^T; counted-vmcnt 2-barrier pipeline;
// XCD-chunked swizzle (768 = 8*96, bijective).
__global__ __launch_bounds__(256, 3) void k_attn(
    const bf16* __restrict__ Qb, const bf16* __restrict__ Kb, const bf16* __restrict__ VbT,
    const float* __restrict__ relh, const float* __restrict__ relw, bf16* __restrict__ attno) {
  __shared__ __align__(16) bf16 Kt[2][64 * 64];   // [key][ch], XOR-swizzled rows
  __shared__ __align__(16) bf16 Vt[2][64 * 64];   // [d][key] (V^T), XOR-swizzled rows
  __shared__ __align__(16) float bH[64 * 33];     // rel_h slice, padded (wave-local rows)
  __shared__ __align__(16) bf16 Pl[4][16 * 64];   // per-wave P transpose buffer, swizzled
  const int blk0 = blockIdx.x;                    // 768 = 48 bn * 16 qtiles
  const int blk = (blk0 & 7) * 96 + (blk0 >> 3);  // XCD-chunked swizzle
  const int bn = blk >> 4, qt = blk & 15;
  const int b = bn / 12, head = bn - b * 12;
  const int tid = threadIdx.x;
  const int lane = tid & 63, w = tid >> 6;
  const int lr = lane & 15, lg = lane >> 4;
  const size_t qkvbase = (size_t)bn * 65536;

  auto stageKV = [&](int kt, int buf) {
#pragma unroll
    for (int c = 0; c < 2; ++c) {
      const int off = c * 4096 + w * 1024 + lane * 16;
      const int row = off >> 7;
      const int loff = off ^ ((row & 7) << 4);  // pre-swizzled global source (rule #21)
      gl_lds16((const char*)Kb + (qkvbase + (size_t)kt * 4096) * 2 + loff,
               (char*)Kt + buf * 8192 + c * 4096 + w * 1024);
      gl_lds16((const char*)VbT + (qkvbase + (size_t)row * 1024 + (size_t)kt * 64) * 2 + (loff & 127),
               (char*)Vt + buf * 8192 + c * 4096 + w * 1024);
    }
  };

  stageKV(0, 0);
  {  // stage bias-H rows for this q-tile (tid>>2 in [w*16,(w+1)*16) -> wave-local)
    const int r = tid >> 2, q8 = (tid & 3) * 8;
    const float* src = relh + (size_t)bn * 32768 + (size_t)(qt * 64 + r) * 32 + q8;
#pragma unroll
    for (int jj = 0; jj < 8; ++jj) bH[r * 33 + q8 + jj] = src[jj];
  }
  const int qrow_g = qt * 64 + w * 16 + lr;
  float bw[2][4];  // bias-W values this lane will need: kw = s1*16 + lg*4 + r
  {
    const float* rw = relw + (size_t)bn * 32768 + (size_t)qrow_g * 32;
#pragma unroll
    for (int s1 = 0; s1 < 2; ++s1)
#pragma unroll
      for (int r = 0; r < 4; ++r) bw[s1][r] = rw[s1 * 16 + lg * 4 + r];
  }
  bf16x8 qf[2];  // Q fragment (B-operand of swapped QK^T), kept in regs
  {
    const char* qp = (const char*)(Qb + qkvbase + (size_t)qrow_g * 64);
    qf[0] = *(const bf16x8*)(qp + lg * 16);
    qf[1] = *(const bf16x8*)(qp + 64 + lg * 16);
  }
  f32x4 oacc[4] = {};   // O^T: lane reg r of dblk = O[q=lr][d = dblk*16 + lg*4 + r]
  float psum = 0.0f;    // per-lane partial row-sum (16 keys/iter), reduced after loop
  int cur = 0;

  for (int kt = 0; kt < 16; ++kt) {
    if (kt + 1 < 16) {
      stageKV(kt + 1, cur ^ 1);                         // 4 more loads in flight
      asm volatile("s_waitcnt vmcnt(4)" ::: "memory");  // stage(kt) landed (this wave)
    } else {
      asm volatile("s_waitcnt vmcnt(0)" ::: "memory");
    }
    __builtin_amdgcn_s_barrier();                       // all waves: Kt/Vt[cur] staged
    const char* Ktc = (const char*)Kt + cur * 8192;
    const char* Vtc = (const char*)Vt + cur * 8192;
    // swapped QK^T: S^T[key][qrow]; lane holds q-row lr, keys s*16 + lg*4 + r
    f32x4 sa[4];
    const int sw = (lr & 7) << 4;
    __builtin_amdgcn_s_setprio(1);
#pragma unroll
    for (int s = 0; s < 4; ++s) {
      const int krow = s * 16 + lr;
      bf16x8 k0 = *(const bf16x8*)(Ktc + ((krow * 128 + lg * 16) ^ sw));
      bf16x8 k1 = *(const bf16x8*)(Ktc + ((krow * 128 + 64 + lg * 16) ^ sw));
      f32x4 z = {};
      z = MFMA16(k0, qf[0], z);
      z = MFMA16(k1, qf[1], z);
      sa[s] = z;
    }
    __builtin_amdgcn_s_setprio(0);
    // p = exp(S*scale + rel_h[qrow][kh] + rel_w[qrow][kw]) -- direct, no max
    const float bh0 = bH[(w * 16 + lr) * 33 + 2 * kt];
    const float bh1 = bH[(w * 16 + lr) * 33 + 2 * kt + 1];
    short4 pk[4];
#pragma unroll
    for (int s = 0; s < 4; ++s) {
      const float bh = (s < 2) ? bh0 : bh1;
#pragma unroll
      for (int r = 0; r < 4; ++r) {
        const float p = __expf(sa[s][r] * 0.125f + bh + bw[s & 1][r]);
        psum += p;
        ((bf16*)&pk[s])[r] = __float2bfloat16(p);
      }
    }
    // P -> LDS (transpose for PV), same XOR swizzle on write & read
#pragma unroll
    for (int s = 0; s < 4; ++s) {
      int byteoff = (lr * 128 + s * 32 + lg * 8) ^ sw;
      *(short4*)((char*)Pl[w] + byteoff) = pk[s];
    }
    asm volatile("s_waitcnt lgkmcnt(0)" ::: "memory");  // P writes visible to wave
    // PV (operand-swapped): O^T += V^T-frag (A) x P^T-frag (B)
    __builtin_amdgcn_s_setprio(1);
#pragma unroll
    for (int kh = 0; kh < 2; ++kh) {
      const int abyte = (lr * 128 + kh * 64 + lg * 16) ^ sw;
      const bf16x8 pa = *(const bf16x8*)((const char*)Pl[w] + abyte);
#pragma unroll
      for (int dblk = 0; dblk < 4; ++dblk) {
        const int vrow = dblk * 16 + lr;
        const bf16x8 vb = *(const bf16x8*)(Vtc + ((vrow * 128 + kh * 64 + lg * 16) ^ sw));
        oacc[dblk] = MFMA16(vb, pa, oacc[dblk]);
      }
    }
    __builtin_amdgcn_s_setprio(0);
    asm volatile("s_waitcnt lgkmcnt(0)" ::: "memory");  // my Vt/Pl ds_reads done
    __builtin_amdgcn_s_barrier();                       // safe to overwrite Kt/Vt[cur]
    cur ^= 1;
  }
  // row-sum reduce over lg groups -> every lane holds its q=lr row sum
  psum += __shfl_xor(psum, 16);
  psum += __shfl_xor(psum, 32);
  const float inv = 1.0f / psum;
#pragma unroll
  for (int dblk = 0; dblk < 4; ++dblk) {
    short4 st;
#pragma unroll
    for (int r = 0; r < 4; ++r)
      ((bf16*)&st)[r] = __float2bfloat16(oacc[dblk][r] * inv);
    *(short4*)(attno + ((size_t)b * 1024 + qrow_g) * 768 + head * 64 + dblk * 16 + lg * 4) = st;
  }
}

// ---------------- output projection GEMM + bias (64x64 tiles, D^T, fp32 out) ----------------
__global__ __launch_bounds__(256, 4) void k_proj(
    const bf16* __restrict__ attno, const bf16* __restrict__ pwb,
    const float* __restrict__ projb, float* __restrict__ out) {
  __shared__ __align__(16) bf16 ldsA[2][64 * 32];
  __shared__ __align__(16) bf16 ldsB[2][64 * 32];
  const int m0 = (blockIdx.x & 63) * 64, n0 = (blockIdx.x >> 6) * 64;  // 64 x 12 tiles
  f32x4 acc[2 * 2] = {};
  gemm_loop<64, 64>(attno, pwb, m0, n0, &ldsA[0][0], &ldsB[0][0], acc);
  const int lane = threadIdx.x & 63, w = threadIdx.x >> 6;
  const int wm = w >> 1, wn = w & 1, lr = lane & 15, lg = lane >> 4;
#pragma unroll
  for (int fm = 0; fm < 2; ++fm) {
    const int m = m0 + wm * 32 + fm * 16 + lr;
#pragma unroll
    for (int fn = 0; fn < 2; ++fn) {
      const int nb = n0 + wn * 32 + fn * 16 + lg * 4;
      const float4 b4 = *(const float4*)(projb + nb);
      const f32x4 a = acc[fm * 2 + fn];
      float4 o{a[0] + b4.x, a[1] + b4.y, a[2] + b4.z, a[3] + b4.w};
      *(float4*)(out + (size_t)m * 768 + nb) = o;
    }
  }
}

// ---------------- launch ----------------
extern "C" void kernel_launch(void* const* d_in, const int* in_sizes, int n_in,
                              void* d_out, int out_size, void* d_ws, size_t ws_size,
                              hipStream_t stream) {
  const float* x     = (const float*)d_in[0];
  const float* qkvw  = (const float*)d_in[1];
  const float* qkvb  = (const float*)d_in[2];
  const float* projw = (const float*)d_in[3];
  const float* projb = (const float*)d_in[4];
  const float* relph = (const float*)d_in[5];
  const float* relpw = (const float*)d_in[6];
  float* out = (float*)d_out;
  char* ws = (char*)d_ws;

  bf16*  xb     = (bf16*)(ws);              // 6,291,456 B
  bf16*  wqkvb  = (bf16*)(ws + 6291456);    // 3,538,944
  bf16*  wprojb = (bf16*)(ws + 9830400);    // 1,179,648
  float* cosT   = (float*)(ws + 11010048);  // 131,072
  float* sinT   = (float*)(ws + 11141120);  // 131,072
  bf16*  Qb     = (bf16*)(ws + 11272192);   // 6,291,456
  bf16*  Kb     = (bf16*)(ws + 17563648);   // 6,291,456
  bf16*  VbT    = (bf16*)(ws + 23855104);   // 6,291,456
  float* relh   = (float*)(ws + 30146560);  // 6,291,456
  float* relw   = (float*)(ws + 36438016);  // 6,291,456
  bf16*  attno  = (bf16*)(ws + 42729472);   // 6,291,456 -> ends 49,020,928

  k_prep<<<5504, 256, 0, stream>>>(x, qkvw, projw, xb, wqkvb, wprojb, cosT, sinT);
  k_qkv<<<1152, 256, 0, stream>>>(xb, wqkvb, qkvb, cosT, sinT, Qb, Kb, VbT);
  k_relbias<<<768, 256, 0, stream>>>(Qb, relph, relpw, relh, relw);
  k_attn<<<768, 256, 0, stream>>>(Qb, Kb, VbT, relh, relw, attno);
  k_proj<<<768, 256, 0, stream>>>(attno, wprojb, projb, out);
}